// Round 1
// baseline (366.376 us; speedup 1.0000x reference)
//
#include <hip/hip_runtime.h>

// Multi-hot encode: out[n, t, x[n, t, f]] = 1.0, everything else 0.
// x: [32, 512, 10] int32, out: [32, 512, 5000] fp32 (~328 MB written/call).
//
// R5: two-dispatch split. R4's LDS staging (zero LDS -> scatter -> barrier ->
// ds_read_b128 -> store) ran at only ~2.7 TB/s effective: 40 KB LDS traffic +
// two barrier drains per 20 KB row, with zero data reuse (common-mistake #7).
// The harness's own fillBufferAligned proves this buffer sustains 6.26 TB/s
// with a pure streaming fill. So:
//   dispatch 1: grid-stride nontemporal dwordx4 zero-fill (the fill pattern).
//   dispatch 2: 163,840-thread scatter of the ones (coalesced index loads,
//               one 4 B store each; ~21 MB of HBM line traffic, ~10 us).
// Stream order between the two dispatches gives the zeros->ones ordering that
// R4 needed intra-block barriers for. No LDS, no barriers in the hot path.

#define NUM_TOKENS 5000
#define NFEAT 10

typedef float vfloat4 __attribute__((ext_vector_type(4)));

__global__ __launch_bounds__(256) void zero_kernel(float* __restrict__ out,
                                                   int nchunks) {
    vfloat4* __restrict__ o4 = reinterpret_cast<vfloat4*>(out);
    const vfloat4 z = {0.f, 0.f, 0.f, 0.f};
    const int stride = gridDim.x * blockDim.x;
    for (int i = blockIdx.x * blockDim.x + threadIdx.x; i < nchunks; i += stride) {
        __builtin_nontemporal_store(z, &o4[i]);
    }
}

__global__ __launch_bounds__(256) void scatter_kernel(const int* __restrict__ x,
                                                      float* __restrict__ out,
                                                      int n) {
    const int i = blockIdx.x * blockDim.x + threadIdx.x;
    if (i < n) {
        const int idx = x[i];            // coalesced 4 B loads
        const int row = i / NFEAT;       // compiler magic-mul, no divide
        out[(size_t)row * NUM_TOKENS + idx] = 1.0f;
    }
}

extern "C" void kernel_launch(void* const* d_in, const int* in_sizes, int n_in,
                              void* d_out, int out_size, void* d_ws, size_t ws_size,
                              hipStream_t stream) {
    const int* x = (const int*)d_in[0];
    float* out = (float*)d_out;
    const int n_idx = in_sizes[0];            // 32*512*10 = 163840 indices
    const int n_rows = n_idx / NFEAT;         // 16384 rows
    const int nchunks = n_rows * (NUM_TOKENS / 4);  // 20,480,000 float4 stores

    // Dispatch 1: stream zeros. 2048 blocks = 8 blocks/CU, grid-stride.
    zero_kernel<<<2048, 256, 0, stream>>>(out, nchunks);

    // Dispatch 2 (stream-ordered after the fill): scatter the ones.
    scatter_kernel<<<(n_idx + 255) / 256, 256, 0, stream>>>(x, out, n_idx);
}

// Round 2
// 340.326 us; speedup vs baseline: 1.0765x; 1.0765x over previous
//
#include <hip/hip_runtime.h>

// Multi-hot encode: out[n, t, x[n, t, f]] = 1.0, everything else 0.
// x: [32, 512, 10] int32, out: [32, 512, 5000] fp32 (~328 MB written/call).
//
// R6: fused block-owns-rows zero+scatter with PLAIN (temporal) stores.
// Evidence: R3/R4/R5 all used __builtin_nontemporal_store and all plateaued
// at ~2.6-3 TB/s effective, while rocclr fillBufferAligned sustains
// 5.6-6.3 TB/s on this very buffer with plain L2-allocating stores. So:
//   - drop nontemporal: plain dwordx4 stores, same pattern as the fast fill.
//   - fuse zero+scatter: block b owns rows [8b, 8b+8) (160 KB contiguous).
//     Zero them, one intra-block __syncthreads (vmcnt drain overlapped by
//     the other 7 resident blocks/CU), then scatter the block's own 80 ones.
//     No cross-block hazard -> no second dispatch, no whole-device sync tail.
// 2048 blocks x 256 threads = 8 blocks/CU, 32 waves/CU (full occupancy).

#define NUM_TOKENS 5000
#define NFEAT 10
#define ROWS_PER_BLOCK 8
#define IDX_PER_BLOCK (ROWS_PER_BLOCK * NFEAT)               // 80
#define CHUNKS_PER_BLOCK (ROWS_PER_BLOCK * NUM_TOKENS / 4)   // 10000 float4s

typedef float vfloat4 __attribute__((ext_vector_type(4)));

__global__ __launch_bounds__(256) void tenhot_fused(const int* __restrict__ x,
                                                    float* __restrict__ out) {
    const int b = blockIdx.x;
    const int tid = threadIdx.x;

    float* __restrict__ base = out + (size_t)b * (ROWS_PER_BLOCK * NUM_TOKENS);
    vfloat4* __restrict__ base4 = reinterpret_cast<vfloat4*>(base);

    // Phase A: stream zeros over this block's 8 rows. Plain stores (like
    // rocclr fill), 16 B/lane, consecutive lanes -> 1 KiB/wave-instruction.
    const vfloat4 z = {0.f, 0.f, 0.f, 0.f};
#pragma unroll 4
    for (int i = tid; i < CHUNKS_PER_BLOCK; i += 256) {
        base4[i] = z;
    }

    // Orders this block's zero-stores before its one-stores (compiler emits
    // s_waitcnt vmcnt(0) + s_barrier). Only ~40 stores/lane outstanding;
    // the drain overlaps with the other 7 blocks resident on this CU.
    __syncthreads();

    // Phase B: scatter this block's 80 ones into its own region. The target
    // lines were just written -> mostly L2-resident, negligible RFO traffic.
    if (tid < IDX_PER_BLOCK) {
        const int idx = x[b * IDX_PER_BLOCK + tid];   // coalesced 4 B loads
        const int r = tid / NFEAT;                    // const divide -> cheap
        base[r * NUM_TOKENS + idx] = 1.0f;
    }
}

extern "C" void kernel_launch(void* const* d_in, const int* in_sizes, int n_in,
                              void* d_out, int out_size, void* d_ws, size_t ws_size,
                              hipStream_t stream) {
    const int* x = (const int*)d_in[0];
    float* out = (float*)d_out;
    const int n_rows = in_sizes[0] / NFEAT;              // 16384
    const int n_blocks = n_rows / ROWS_PER_BLOCK;        // 2048 = 8 blocks/CU
    tenhot_fused<<<n_blocks, 256, 0, stream>>>(x, out);
}

// Round 3
// 339.022 us; speedup vs baseline: 1.0807x; 1.0038x over previous
//
#include <hip/hip_runtime.h>

// Multi-hot encode: out[n, t, x[n, t, f]] = 1.0, everything else 0.
// x: [32, 512, 10] int32, out: [32, 512, 5000] fp32 (~328 MB written/call).
//
// R7: per-WAVE ownership, barrier-free. R6 (block owns 8 rows, full
// __syncthreads between zero and scatter) left ~15-20 us of inter-wave
// coupling + exposed index-load latency. Here wave w owns rows
// [2w, 2w+2) (40 KB contiguous) and that region's 20 ones, so the
// zero->one ordering needs only a per-wave s_waitcnt vmcnt(0): same-wave
// stores to the same address are ordered once the first has retired to the
// coherence point (L2). No s_barrier anywhere; waves never wait on each
// other. Index loads are issued BEFORE the 39-iteration zero loop so their
// latency hides under the store stream.
//
// Floor model: the harness poison fill writes 1.31 GB to this buffer right
// before us at ~5.7-6.3 TB/s; its L3-dirty tail (~250 MB) drains during our
// kernel, so our 328 MB write runs drain-contended: floor ~90 us, total
// window floor ~262 us + resets. R6 residual was ~110 us; this targets the
// last structural overhead.

#define NUM_TOKENS 5000
#define NFEAT 10
#define ROWS_PER_WAVE 2
#define ROWS_PER_BLOCK 8                                  // 4 waves/block
#define CHUNKS_PER_WAVE (ROWS_PER_WAVE * NUM_TOKENS / 4)  // 2500 float4s
#define IDX_PER_WAVE (ROWS_PER_WAVE * NFEAT)              // 20

typedef float vfloat4 __attribute__((ext_vector_type(4)));

__global__ __launch_bounds__(256) void tenhot_wave(const int* __restrict__ x,
                                                   float* __restrict__ out) {
    const int tid = threadIdx.x;
    const int wave = tid >> 6;
    const int lane = tid & 63;
    const int row0 = blockIdx.x * ROWS_PER_BLOCK + wave * ROWS_PER_WAVE;

    float* __restrict__ base = out + (size_t)row0 * NUM_TOKENS;
    vfloat4* __restrict__ base4 = reinterpret_cast<vfloat4*>(base);

    // Issue this wave's 20 index loads up front; latency hides under the
    // zero-store stream below (the vmcnt(0) wait covers it too).
    int idx = 0;
    if (lane < IDX_PER_WAVE) {
        idx = x[row0 * NFEAT + lane];
    }

    // Zero-stream this wave's 2 rows (40 KB): 16 B/lane plain stores,
    // 1 KiB per wave-instruction, ~39 iterations.
    const vfloat4 z = {0.f, 0.f, 0.f, 0.f};
#pragma unroll 5
    for (int i = lane; i < CHUNKS_PER_WAVE; i += 64) {
        base4[i] = z;
    }

    // Per-wave drain: all zero-stores (and the idx load) retired to the
    // coherence point. Cheaper than s_barrier - no cross-wave wait.
    asm volatile("s_waitcnt vmcnt(0)" ::: "memory");

    // Scatter this wave's 20 ones into its own 2 rows (L2-resident lines).
    if (lane < IDX_PER_WAVE) {
        const int r = lane / NFEAT;  // 0 or 1, const divide
        base[r * NUM_TOKENS + idx] = 1.0f;
    }
}

extern "C" void kernel_launch(void* const* d_in, const int* in_sizes, int n_in,
                              void* d_out, int out_size, void* d_ws, size_t ws_size,
                              hipStream_t stream) {
    const int* x = (const int*)d_in[0];
    float* out = (float*)d_out;
    const int n_rows = in_sizes[0] / NFEAT;        // 16384
    const int n_blocks = n_rows / ROWS_PER_BLOCK;  // 2048 = 8 blocks/CU
    tenhot_wave<<<n_blocks, 256, 0, stream>>>(x, out);
}